// Round 1
// baseline (7917.253 us; speedup 1.0000x reference)
//
#include <hip/hip_runtime.h>
#include <hip/hip_bf16.h>

// Decoder: T=50 steps, B=64, S=400, V=50000, D=E=H=A=512, POOL=2.
// Strategy: MFMA bf16 precompute of all emb/ctx/gctx-dependent GEMMs,
// 4 small kernels per scan step (gru, q, energy, softmax+context),
// post-pass batched readout/pgen/maxout.

#define T_STEPS 50
#define BB 64
#define SS 400

// output offsets (floats)
#define O_GOUT 0
#define O_HID 819200
#define O_ATTN_LAST 851968
#define O_CTXF 877568
#define O_PG 910336
#define O_GATTN 913536
#define O_COVL 2193536
#define O_COVF 2196736

static __device__ __forceinline__ float bf2f(unsigned short u){
  unsigned v = ((unsigned)u) << 16; return __builtin_bit_cast(float, v);
}
static __device__ __forceinline__ unsigned short f2bf(float f){
  unsigned u = __builtin_bit_cast(unsigned, f);
  unsigned r = (u + 0x7FFFu + ((u >> 16) & 1u)) >> 16;
  return (unsigned short)r;
}
static __device__ __forceinline__ float sigmoidf_(float x){ return 1.f/(1.f+__expf(-x)); }
static __device__ __forceinline__ float tanhf_(float x){ float e=__expf(2.f*x); return 1.f - 2.f/(e+1.f); }

// ---------------- converts ----------------
__global__ void conv_ctx(const float* __restrict__ ctx, unsigned short* __restrict__ out){
  int o = blockIdx.x*256 + threadIdx.x;           // [S][B][E] -> [B][S][E] bf16
  if(o >= SS*BB*512) return;
  int e = o & 511; int b = (o>>9)&63; int s = o>>15;
  out[((b*SS+s)<<9) + e] = f2bf(ctx[o]);
}
__global__ void conv_emb(const int* __restrict__ y, const float* __restrict__ embW,
                         unsigned short* __restrict__ embU){
  int o = blockIdx.x*256+threadIdx.x; if(o>=T_STEPS*BB*512) return;
  int d = o & 511; int i = o>>9;
  embU[o] = f2bf(embW[(long)y[i]*512 + d]);
}
__global__ void conv_wihd(const float* __restrict__ W_ih, unsigned short* __restrict__ out){
  int o = blockIdx.x*256+threadIdx.x; if(o>=1536*512) return;
  int j = o>>9; int d = o&511;
  out[o] = f2bf(W_ih[(long)j*1024 + d]);
}
__global__ void conv_preT(const float* __restrict__ W_pre, unsigned short* __restrict__ out){
  int o = blockIdx.x*256+threadIdx.x; if(o>=512*512) return;
  int a = o>>9; int e = o&511;
  out[o] = f2bf(W_pre[(long)e*512 + a]);     // out[a][e]
}
__global__ void conv_roT(const float* __restrict__ W_ro, unsigned short* __restrict__ out){
  int o = blockIdx.x*256+threadIdx.x; if(o>=512*2048) return;
  int n = o>>11; int k = o&2047;
  out[o] = f2bf(W_ro[(long)k*512 + n]);      // out[n][k]
}
__global__ void k_init(const float* __restrict__ hidden, const float* __restrict__ init_att,
                       const float* __restrict__ gctx, const float* __restrict__ coverage,
                       float* __restrict__ hT0, float* __restrict__ ctxT,
                       float* __restrict__ gctxT, float* __restrict__ cov){
  int o = blockIdx.x*256+threadIdx.x;
  if(o < 32768){ int b=o>>9, k=o&511; hT0[k*64+b] = hidden[o]; }
  else if(o < 65536){ int p=o-32768; int b=p>>9,e=p&511; ctxT[e*64+b]=init_att[p]; }
  else if(o < 98304){ int p=o-65536; int b=p>>9,e=p&511; gctxT[e*64+b]=gctx[p]; }
  else if(o < 98304+25600){ int p=o-98304; cov[p]=coverage[p]; }
}

// ---------------- MFMA GEMM: C[M][N] = A[M][K](bf16,row-major) * B[N][Ktot](bf16,n-major)^T ----------
// tile 128x128, 4 waves (2x2), BK=32, LDS stride 40 (pad 8) to keep 16B alignment + low conflicts.
template<int OUT_BF16, int ACCUM>
__global__ __launch_bounds__(256) void mfma_gemm(
    const unsigned short* __restrict__ Abf, int lda,
    const unsigned short* __restrict__ Bbf, int ldb, int koff,
    void* __restrict__ Cp, int ldc, const float* __restrict__ bias, int K)
{
  __shared__ __align__(16) unsigned short Ash[128*40];
  __shared__ __align__(16) unsigned short Bsh[128*40];
  int m0 = blockIdx.x*128, n0 = blockIdx.y*128;
  int tid = threadIdx.x;
  int wid = tid>>6, lane = tid&63;
  int wm = wid>>1, wn = wid&1;
  int lr = lane&15, lg = lane>>4;
  typedef __attribute__((ext_vector_type(4))) float f4;
  typedef __attribute__((ext_vector_type(8))) short s8v;
  f4 acc[4][4];
  #pragma unroll
  for(int i=0;i<4;i++)
    #pragma unroll
    for(int j=0;j<4;j++) acc[i][j]=(f4)0.f;

  for(int kt=0; kt<K; kt+=32){
    #pragma unroll
    for(int c=0;c<2;c++){
      int flat = tid*16 + c*8;
      int row = flat>>5, col = flat&31;
      const unsigned short* ga = Abf + (long)(m0+row)*lda + kt + col;
      *(uint4*)(&Ash[row*40+col]) = *(const uint4*)ga;
      const unsigned short* gb = Bbf + (long)(n0+row)*ldb + koff + kt + col;
      *(uint4*)(&Bsh[row*40+col]) = *(const uint4*)gb;
    }
    __syncthreads();
    s8v av[4], bv[4];
    #pragma unroll
    for(int mi=0;mi<4;mi++) av[mi] = *(const s8v*)(&Ash[(wm*64+mi*16+lr)*40 + lg*8]);
    #pragma unroll
    for(int ni=0;ni<4;ni++) bv[ni] = *(const s8v*)(&Bsh[(wn*64+ni*16+lr)*40 + lg*8]);
    #pragma unroll
    for(int mi=0;mi<4;mi++)
      #pragma unroll
      for(int ni=0;ni<4;ni++)
        acc[mi][ni] = __builtin_amdgcn_mfma_f32_16x16x32_bf16(av[mi], bv[ni], acc[mi][ni], 0,0,0);
    __syncthreads();
  }
  #pragma unroll
  for(int mi=0;mi<4;mi++)
    #pragma unroll
    for(int ni=0;ni<4;ni++){
      int gc = n0 + wn*64 + ni*16 + lr;
      #pragma unroll
      for(int r=0;r<4;r++){
        int gr = m0 + wm*64 + mi*16 + lg*4 + r;
        float v = acc[mi][ni][r];
        if(bias) v += bias[gc];
        if(OUT_BF16){
          ((unsigned short*)Cp)[(long)gr*ldc + gc] = f2bf(v);
        } else {
          float* C = (float*)Cp;
          if(ACCUM) v += C[(long)gr*ldc+gc];
          C[(long)gr*ldc+gc] = v;
        }
      }
    }
}

// ---------------- small fp32 GEMM: out[64][N] = addend + AT[K][64]^T * W[koff+k][N] ----------
__global__ __launch_bounds__(256) void small_gemm_kn(
  const float* __restrict__ AT, const float* __restrict__ W, int koff, int N,
  const float* __restrict__ addend, float* __restrict__ out, int K)
{
  int tid = threadIdx.x;
  int b = tid&63; int nq = tid>>6;
  int n = __builtin_amdgcn_readfirstlane(blockIdx.x*4 + nq);
  float acc = addend ? addend[b*N+n] : 0.f;
  const float* wp = W + (long)koff*N + n;
  #pragma unroll 8
  for(int k=0;k<K;k++){
    acc = fmaf(AT[k*64+b], wp[(long)k*N], acc);
  }
  out[b*N+n] = acc;
}

// ---------------- GRU step (fused gates) ----------------
__global__ __launch_bounds__(256) void k_gru(
  const float* __restrict__ ctxT, const float* __restrict__ hT_in, float* __restrict__ hT_out,
  const float* __restrict__ gi_emb, const float* __restrict__ W_ih, const float* __restrict__ W_hh,
  const float* __restrict__ b_hh, unsigned short* __restrict__ h0bf_all, int t)
{
  int tid=threadIdx.x; int b=tid&63; int jq=tid>>6;
  int j = __builtin_amdgcn_readfirstlane(blockIdx.x*4 + jq);
  const float* wir = W_ih + (long)j*1024 + 512;
  const float* wiz = W_ih + (long)(j+512)*1024 + 512;
  const float* win = W_ih + (long)(j+1024)*1024 + 512;
  const float* whr = W_hh + (long)j*512;
  const float* whz = W_hh + (long)(j+512)*512;
  const float* whn = W_hh + (long)(j+1024)*512;
  float air=0,aiz=0,ain=0,ahr=0,ahz=0,ahn=0;
  #pragma unroll 4
  for(int k=0;k<512;k++){
    float cc = ctxT[k*64+b]; float hh = hT_in[k*64+b];
    air = fmaf(cc, wir[k], air); aiz = fmaf(cc, wiz[k], aiz); ain = fmaf(cc, win[k], ain);
    ahr = fmaf(hh, whr[k], ahr); ahz = fmaf(hh, whz[k], ahz); ahn = fmaf(hh, whn[k], ahn);
  }
  int m = t*64 + b;
  const float* ge = gi_emb + (long)m*1536;
  float hr = b_hh[j] + ahr;
  float hz = b_hh[512+j] + ahz;
  float hn = b_hh[1024+j] + ahn;
  float r  = sigmoidf_(ge[j] + air + hr);
  float z  = sigmoidf_(ge[512+j] + aiz + hz);
  float n_ = tanhf_(ge[1024+j] + ain + r*hn);
  float hprev = hT_in[j*64+b];
  float hv = (1.f-z)*n_ + z*hprev;
  hT_out[j*64+b] = hv;
  h0bf_all[(long)m*512 + j] = f2bf(hv);
}

// ---------------- attention energy ----------------
__global__ __launch_bounds__(256) void k_energy(
  const unsigned short* __restrict__ pre, const float* __restrict__ q,
  const float* __restrict__ cov, const float* __restrict__ Wv, const float* __restrict__ Wcov,
  const float* __restrict__ pad, float* __restrict__ energy)
{
  int sc = blockIdx.x; int b = blockIdx.y;
  int tid=threadIdx.x; int wid=tid>>6; int lane=tid&63;
  float qv[8], wvv[8], wcv[8];
  #pragma unroll
  for(int kk=0;kk<4;kk++){
    int a0 = kk*128 + lane*2;
    qv[kk*2]=q[b*512+a0]; qv[kk*2+1]=q[b*512+a0+1];
    wvv[kk*2]=Wv[a0]; wvv[kk*2+1]=Wv[a0+1];
    wcv[kk*2]=Wcov[a0]; wcv[kk*2+1]=Wcov[a0+1];
  }
  for(int si=wid; si<50; si+=4){
    int s = sc*50+si;
    float cv = cov[b*400+s];
    const unsigned short* rp = pre + ((long)(b*400+s)<<9);
    float part = 0.f;
    #pragma unroll
    for(int kk=0;kk<4;kk++){
      unsigned u = *(const unsigned*)(rp + kk*128 + lane*2);
      float lo = bf2f((unsigned short)(u&0xffffu));
      float hi = bf2f((unsigned short)(u>>16));
      part += wvv[kk*2]  *tanhf_(lo + qv[kk*2]   + cv*wcv[kk*2]);
      part += wvv[kk*2+1]*tanhf_(hi + qv[kk*2+1] + cv*wcv[kk*2+1]);
    }
    #pragma unroll
    for(int off=32; off; off>>=1) part += __shfl_xor(part, off, 64);
    if(lane==0){
      energy[b*400+s] = (pad[b*400+s] > 0.5f) ? -1e18f : part;
    }
  }
}

// ---------------- softmax + coverage + weighted context ----------------
__global__ __launch_bounds__(256) void k_context(
  const float* __restrict__ energy, float* __restrict__ cov,
  const unsigned short* __restrict__ ctxbf, float* __restrict__ ctxT_out,
  unsigned short* __restrict__ ctx_all, float* __restrict__ outp, int t)
{
  __shared__ float red[256];
  __shared__ float attn_sh[400];
  __shared__ float pb[4][256];
  int ec = blockIdx.x; int b = blockIdx.y; int tid=threadIdx.x;
  float v1 = energy[b*400+tid];
  bool has2 = tid<144;
  float v2 = has2 ? energy[b*400+256+tid] : -INFINITY;
  red[tid] = fmaxf(v1,v2); __syncthreads();
  for(int o=128;o;o>>=1){ if(tid<o) red[tid]=fmaxf(red[tid],red[tid+o]); __syncthreads(); }
  float mx = red[0]; __syncthreads();
  float p1 = __expf(v1-mx); float p2 = has2? __expf(v2-mx) : 0.f;
  red[tid] = p1+p2; __syncthreads();
  for(int o=128;o;o>>=1){ if(tid<o) red[tid]+=red[tid+o]; __syncthreads(); }
  float inv = 1.f/red[0]; __syncthreads();
  float a1 = p1*inv; float a2 = p2*inv;
  attn_sh[tid] = a1; if(has2) attn_sh[256+tid] = a2;
  if(ec==0){
    float* gat = outp + O_GATTN + (long)t*25600 + b*400;
    gat[tid] = a1;
    float c1 = cov[b*400+tid];
    float cl = fminf(a1,c1);
    cov[b*400+tid] = c1+a1;
    if(has2){
      gat[256+tid]=a2;
      float c2 = cov[b*400+256+tid];
      cl += fminf(a2,c2);
      cov[b*400+256+tid] = c2+a2;
    }
    red[tid]=cl; __syncthreads();
    for(int o=128;o;o>>=1){ if(tid<o) red[tid]+=red[tid+o]; __syncthreads(); }
    if(tid==0) outp[O_COVL + t*64 + b] = red[0];
  }
  __syncthreads();
  // phase B: cur_ctx over e-slice [ec*128, ec*128+128)
  int ep = tid&63; int sp = tid>>6;
  int e = ec*128 + ep*2;
  float acc0=0.f, acc1=0.f;
  for(int s=sp; s<400; s+=4){
    float av = attn_sh[s];
    unsigned u = *(const unsigned*)(ctxbf + ((long)(b*400+s)<<9) + e);
    acc0 = fmaf(av, bf2f((unsigned short)(u&0xffffu)), acc0);
    acc1 = fmaf(av, bf2f((unsigned short)(u>>16)), acc1);
  }
  pb[sp][ep*2]=acc0; pb[sp][ep*2+1]=acc1; __syncthreads();
  if(tid<128){
    int c = tid; int eg = ec*128 + c;
    float sum = pb[0][c]+pb[1][c]+pb[2][c]+pb[3][c];
    ctxT_out[eg*64+b] = sum;
    ctx_all[((long)(t*64+b)<<9)+eg] = f2bf(sum);
    if(t==T_STEPS-1) outp[O_CTXF + b*512 + eg] = sum;
  }
}

// ---------------- post-pass ----------------
__global__ __launch_bounds__(256) void k_pgen(
  const unsigned short* __restrict__ embU, const unsigned short* __restrict__ h0bf,
  const unsigned short* __restrict__ ctxA, const float* __restrict__ Wpg,
  const float* __restrict__ bpg, float* __restrict__ outp)
{
  int wid = threadIdx.x>>6, lane=threadIdx.x&63;
  int m = blockIdx.x*4 + wid;
  float acc=0.f;
  #pragma unroll
  for(int i=0;i<8;i++){
    int k = i*64+lane;
    acc = fmaf(bf2f(ctxA[(long)m*512+k]), Wpg[k], acc);
    acc = fmaf(bf2f(h0bf[(long)m*512+k]), Wpg[512+k], acc);
    acc = fmaf(bf2f(embU[(long)m*512+k]), Wpg[1024+k], acc);
  }
  #pragma unroll
  for(int off=32; off; off>>=1) acc += __shfl_xor(acc, off, 64);
  if(lane==0) outp[O_PG + m] = sigmoidf_(acc + bpg[0]);
}

__global__ void k_maxout(const float* __restrict__ RO, const float* __restrict__ ro_g,
                         float* __restrict__ outp){
  int o = blockIdx.x*256+threadIdx.x; if(o>=819200) return;
  int h = o & 255; int m = o>>8; int b = m & 63;
  float v0 = RO[(long)m*512 + 2*h]   + ro_g[b*512 + 2*h];
  float v1 = RO[(long)m*512 + 2*h+1] + ro_g[b*512 + 2*h+1];
  outp[O_GOUT + o] = fmaxf(v0,v1);
}

__global__ void k_final(const float* __restrict__ hT0, const float* __restrict__ cov,
                        float* __restrict__ outp){
  int o = blockIdx.x*256+threadIdx.x;
  if(o < 32768){ int b=o>>9, k=o&511; outp[O_HID + o] = hT0[k*64+b]; }
  else if(o < 58368){ int p=o-32768; outp[O_ATTN_LAST+p] = outp[O_GATTN + 49*25600 + p]; }
  else if(o < 83968){ int p=o-58368; outp[O_COVF+p] = cov[p]; }
}

extern "C" void kernel_launch(void* const* d_in, const int* in_sizes, int n_in,
                              void* d_out, int out_size, void* d_ws, size_t ws_size,
                              hipStream_t stream)
{
  (void)in_sizes; (void)n_in; (void)out_size; (void)ws_size;
  const int*   y       = (const int*)d_in[0];
  const float* hidden  = (const float*)d_in[1];
  const float* context = (const float*)d_in[2];
  const float* padm    = (const float*)d_in[3];
  const float* init_att= (const float*)d_in[4];
  const float* coverage= (const float*)d_in[5];
  const float* gctx    = (const float*)d_in[6];
  const float* embW    = (const float*)d_in[7];
  const float* W_ih    = (const float*)d_in[8];
  const float* W_hh    = (const float*)d_in[9];
  const float* b_ih    = (const float*)d_in[10];
  const float* b_hh    = (const float*)d_in[11];
  const float* W_pre   = (const float*)d_in[12];
  const float* b_pre   = (const float*)d_in[13];
  const float* W_q     = (const float*)d_in[14];
  const float* W_v     = (const float*)d_in[15];
  const float* W_cov   = (const float*)d_in[16];
  const float* W_pg    = (const float*)d_in[17];
  const float* b_pg    = (const float*)d_in[18];
  const float* W_ro    = (const float*)d_in[19];
  const float* b_ro    = (const float*)d_in[20];
  float* out = (float*)d_out;

  char* wsb = (char*)d_ws;
  size_t off = 0;
  auto alloc = [&](size_t bytes)->char*{ char* p = wsb+off; off += (bytes+255)&~255UL; return p; };
  unsigned short* pre    = (unsigned short*)alloc(25600UL*512*2);
  unsigned short* ctxbf  = (unsigned short*)alloc(13107200UL*2);
  unsigned short* embU   = (unsigned short*)alloc(3200UL*512*2);
  unsigned short* wihbf  = (unsigned short*)alloc(1536UL*512*2);
  unsigned short* wpreT  = (unsigned short*)alloc(512UL*512*2);
  unsigned short* wroT   = (unsigned short*)alloc(512UL*2048*2);
  float* gi_emb = (float*)alloc(3200UL*1536*4);
  float* RO     = (float*)alloc(3200UL*512*4);
  float* q_g    = (float*)alloc(64UL*512*4);
  float* ro_g   = (float*)alloc(64UL*512*4);
  float* hT0    = (float*)alloc(512UL*64*4);
  float* hT1    = (float*)alloc(512UL*64*4);
  float* ctxT   = (float*)alloc(512UL*64*4);
  float* gctxT  = (float*)alloc(512UL*64*4);
  unsigned short* h0bf = (unsigned short*)alloc(3200UL*512*2);
  unsigned short* ctxA = (unsigned short*)alloc(3200UL*512*2);
  float* qbuf   = (float*)alloc(64UL*512*4);
  float* energy = (float*)alloc(64UL*400*4);
  float* cov    = (float*)alloc(64UL*400*4);

  // converts + init
  conv_ctx <<<dim3(51200),dim3(256),0,stream>>>(context, ctxbf);
  conv_emb <<<dim3(6400), dim3(256),0,stream>>>(y, embW, embU);
  conv_wihd<<<dim3(3072), dim3(256),0,stream>>>(W_ih, wihbf);
  conv_preT<<<dim3(1024), dim3(256),0,stream>>>(W_pre, wpreT);
  conv_roT <<<dim3(4096), dim3(256),0,stream>>>(W_ro, wroT);
  k_init   <<<dim3(485),  dim3(256),0,stream>>>(hidden, init_att, gctx, coverage, hT0, ctxT, gctxT, cov);

  // precompute GEMMs
  mfma_gemm<1,0><<<dim3(200,4),dim3(256),0,stream>>>(ctxbf,512, wpreT,512,0,  pre,   512, b_pre, 512);
  mfma_gemm<0,0><<<dim3(25,12),dim3(256),0,stream>>>(embU, 512, wihbf,512,0,  gi_emb,1536,b_ih, 512);
  mfma_gemm<0,0><<<dim3(25,4), dim3(256),0,stream>>>(embU, 512, wroT,2048,0,  RO,    512, b_ro, 512);
  small_gemm_kn<<<dim3(128),dim3(256),0,stream>>>(gctxT, W_q, 512, 512, nullptr, q_g, 512);
  small_gemm_kn<<<dim3(128),dim3(256),0,stream>>>(gctxT, W_ro,1536, 512, nullptr, ro_g, 512);

  // scan
  for(int t=0; t<T_STEPS; t++){
    float* hin  = (t&1) ? hT1 : hT0;
    float* hout = (t&1) ? hT0 : hT1;
    k_gru<<<dim3(128),dim3(256),0,stream>>>(ctxT, hin, hout, gi_emb, W_ih, W_hh, b_hh, h0bf, t);
    small_gemm_kn<<<dim3(128),dim3(256),0,stream>>>(hout, W_q, 0, 512, q_g, qbuf, 512);
    k_energy<<<dim3(8,64),dim3(256),0,stream>>>(pre, qbuf, cov, W_v, W_cov, padm, energy);
    k_context<<<dim3(4,64),dim3(256),0,stream>>>(energy, cov, ctxbf, ctxT, ctxA, out, t);
  }

  // post-pass
  mfma_gemm<0,1><<<dim3(25,4),dim3(256),0,stream>>>(h0bf,512, wroT,2048,512,  RO,512, nullptr, 512);
  mfma_gemm<0,1><<<dim3(25,4),dim3(256),0,stream>>>(ctxA,512, wroT,2048,1024, RO,512, nullptr, 512);
  k_pgen  <<<dim3(800), dim3(256),0,stream>>>(embU, h0bf, ctxA, W_pg, b_pg, out);
  k_maxout<<<dim3(3200),dim3(256),0,stream>>>(RO, ro_g, out);
  k_final <<<dim3(328), dim3(256),0,stream>>>(hT0, cov, out);
}

// Round 2
// 4907.894 us; speedup vs baseline: 1.6132x; 1.6132x over previous
//
#include <hip/hip_runtime.h>
#include <hip/hip_bf16.h>

// Decoder: T=50 steps, B=64, S=400, V=50000, D=E=H=A=512, POOL=2.
// R2: MFMA-based GRU (fragment-packed bf16 weights) + MFMA q-GEMM.

#define T_STEPS 50
#define BB 64
#define SS 400

// output offsets (floats)
#define O_GOUT 0
#define O_HID 819200
#define O_ATTN_LAST 851968
#define O_CTXF 877568
#define O_PG 910336
#define O_GATTN 913536
#define O_COVL 2193536
#define O_COVF 2196736

typedef __attribute__((ext_vector_type(4))) float f4;
typedef __attribute__((ext_vector_type(8))) short s8v;

static __device__ __forceinline__ float bf2f(unsigned short u){
  unsigned v = ((unsigned)u) << 16; return __builtin_bit_cast(float, v);
}
static __device__ __forceinline__ unsigned short f2bf(float f){
  unsigned u = __builtin_bit_cast(unsigned, f);
  unsigned r = (u + 0x7FFFu + ((u >> 16) & 1u)) >> 16;
  return (unsigned short)r;
}
static __device__ __forceinline__ float sigmoidf_(float x){ return 1.f/(1.f+__expf(-x)); }
static __device__ __forceinline__ float tanhf_(float x){ float e=__expf(2.f*x); return 1.f - 2.f/(e+1.f); }

// ---------------- converts ----------------
__global__ void conv_ctx(const float* __restrict__ ctx, unsigned short* __restrict__ out){
  int o = blockIdx.x*256 + threadIdx.x;           // [S][B][E] -> [B][S][E] bf16
  if(o >= SS*BB*512) return;
  int e = o & 511; int b = (o>>9)&63; int s = o>>15;
  out[((b*SS+s)<<9) + e] = f2bf(ctx[o]);
}
__global__ void conv_emb(const int* __restrict__ y, const float* __restrict__ embW,
                         unsigned short* __restrict__ embU){
  int o = blockIdx.x*256+threadIdx.x; if(o>=T_STEPS*BB*512) return;
  int d = o & 511; int i = o>>9;
  embU[o] = f2bf(embW[(long)y[i]*512 + d]);
}
__global__ void conv_wihd(const float* __restrict__ W_ih, unsigned short* __restrict__ out){
  int o = blockIdx.x*256+threadIdx.x; if(o>=1536*512) return;
  int j = o>>9; int d = o&511;
  out[o] = f2bf(W_ih[(long)j*1024 + d]);           // D-part for gi_emb precompute
}
__global__ void conv_preT(const float* __restrict__ W_pre, unsigned short* __restrict__ out){
  int o = blockIdx.x*256+threadIdx.x; if(o>=512*512) return;
  int a = o>>9; int e = o&511;
  out[o] = f2bf(W_pre[(long)e*512 + a]);     // out[a][e]
}
__global__ void conv_roT(const float* __restrict__ W_ro, unsigned short* __restrict__ out){
  int o = blockIdx.x*256+threadIdx.x; if(o>=512*2048) return;
  int n = o>>11; int k = o&2047;
  out[o] = f2bf(W_ro[(long)k*512 + n]);      // out[n][k]
}
// pack GRU weights fragment-ordered: Wp[rg=blk*24+w*6+g*2+op][ki][lane][8]
// rg row block of 16 rows: d = blk*64+w*16+rl, j = g*512+d; op0 = W_ih E-part, op1 = W_hh
__global__ void conv_wgru(const float* __restrict__ W_ih, const float* __restrict__ W_hh,
                          unsigned short* __restrict__ Wp){
  int o = blockIdx.x*256+threadIdx.x; if(o >= 192*8192) return;
  int rg = o >> 13; int rem = o & 8191;
  int ki = rem >> 9; int ln = (rem >> 3) & 63; int e = o & 7;
  int blk = rg/24; int r2 = rg%24; int w = r2/6; int r3 = r2%6; int g = r3>>1; int op = r3&1;
  int rl = ln & 15; int kk = ((ln>>4)<<3) + e;
  int d = blk*64 + w*16 + rl; int j = g*512 + d; int k = ki*32 + kk;
  float v = op ? W_hh[(long)j*512 + k] : W_ih[(long)j*1024 + 512 + k];
  Wp[o] = f2bf(v);
}
// pack W_q (h-part, rows k<512) fragment-ordered: rows n, k contiguous frags
__global__ void conv_wq(const float* __restrict__ W_q, unsigned short* __restrict__ Wp){
  int o = blockIdx.x*256+threadIdx.x; if(o >= 32*8192) return;
  int rg = o >> 13; int rem = o & 8191;
  int ki = rem >> 9; int ln = (rem >> 3) & 63; int e = o & 7;
  int rl = ln & 15; int kk = ((ln>>4)<<3) + e;
  int n = rg*16 + rl; int k = ki*32 + kk;
  Wp[o] = f2bf(W_q[(long)k*512 + n]);
}
__global__ void k_init(const float* __restrict__ hidden, const float* __restrict__ init_att,
                       const float* __restrict__ gctx, const float* __restrict__ coverage,
                       float* __restrict__ hrow0, unsigned short* __restrict__ h0bf_init,
                       unsigned short* __restrict__ ctx0bf,
                       float* __restrict__ gctxT, float* __restrict__ cov){
  int o = blockIdx.x*256+threadIdx.x;
  if(o < 32768){ float v = hidden[o]; hrow0[o] = v; h0bf_init[o] = f2bf(v); }
  else if(o < 65536){ int p=o-32768; ctx0bf[p] = f2bf(init_att[p]); }
  else if(o < 98304){ int p=o-65536; int b=p>>9,e=p&511; gctxT[e*64+b]=gctx[p]; }
  else if(o < 98304+25600){ int p=o-98304; cov[p]=coverage[p]; }
}

// ---------------- MFMA GEMM: C[M][N] = A[M][K](bf16,row-major) * B[N][Ktot](bf16,n-major)^T ----------
template<int OUT_BF16, int ACCUM>
__global__ __launch_bounds__(256) void mfma_gemm(
    const unsigned short* __restrict__ Abf, int lda,
    const unsigned short* __restrict__ Bbf, int ldb, int koff,
    void* __restrict__ Cp, int ldc, const float* __restrict__ bias, int K)
{
  __shared__ __align__(16) unsigned short Ash[128*40];
  __shared__ __align__(16) unsigned short Bsh[128*40];
  int m0 = blockIdx.x*128, n0 = blockIdx.y*128;
  int tid = threadIdx.x;
  int wid = tid>>6, lane = tid&63;
  int wm = wid>>1, wn = wid&1;
  int lr = lane&15, lg = lane>>4;
  f4 acc[4][4];
  #pragma unroll
  for(int i=0;i<4;i++)
    #pragma unroll
    for(int j=0;j<4;j++) acc[i][j]=(f4)0.f;

  for(int kt=0; kt<K; kt+=32){
    #pragma unroll
    for(int c=0;c<2;c++){
      int flat = tid*16 + c*8;
      int row = flat>>5, col = flat&31;
      const unsigned short* ga = Abf + (long)(m0+row)*lda + kt + col;
      *(uint4*)(&Ash[row*40+col]) = *(const uint4*)ga;
      const unsigned short* gb = Bbf + (long)(n0+row)*ldb + koff + kt + col;
      *(uint4*)(&Bsh[row*40+col]) = *(const uint4*)gb;
    }
    __syncthreads();
    s8v av[4], bv[4];
    #pragma unroll
    for(int mi=0;mi<4;mi++) av[mi] = *(const s8v*)(&Ash[(wm*64+mi*16+lr)*40 + lg*8]);
    #pragma unroll
    for(int ni=0;ni<4;ni++) bv[ni] = *(const s8v*)(&Bsh[(wn*64+ni*16+lr)*40 + lg*8]);
    #pragma unroll
    for(int mi=0;mi<4;mi++)
      #pragma unroll
      for(int ni=0;ni<4;ni++)
        acc[mi][ni] = __builtin_amdgcn_mfma_f32_16x16x32_bf16(av[mi], bv[ni], acc[mi][ni], 0,0,0);
    __syncthreads();
  }
  #pragma unroll
  for(int mi=0;mi<4;mi++)
    #pragma unroll
    for(int ni=0;ni<4;ni++){
      int gc = n0 + wn*64 + ni*16 + lr;
      #pragma unroll
      for(int r=0;r<4;r++){
        int gr = m0 + wm*64 + mi*16 + lg*4 + r;
        float v = acc[mi][ni][r];
        if(bias) v += bias[gc];
        if(OUT_BF16){
          ((unsigned short*)Cp)[(long)gr*ldc + gc] = f2bf(v);
        } else {
          float* C = (float*)Cp;
          if(ACCUM) v += C[(long)gr*ldc+gc];
          C[(long)gr*ldc+gc] = v;
        }
      }
    }
}

// ---------------- small fp32 GEMM (one-time precompute only) ----------------
__global__ __launch_bounds__(256) void small_gemm_kn(
  const float* __restrict__ AT, const float* __restrict__ W, int koff, int N,
  const float* __restrict__ addend, float* __restrict__ out, int K)
{
  int tid = threadIdx.x;
  int b = tid&63; int nq = tid>>6;
  int n = __builtin_amdgcn_readfirstlane(blockIdx.x*4 + nq);
  float acc = addend ? addend[b*N+n] : 0.f;
  const float* wp = W + (long)koff*N + n;
  #pragma unroll 8
  for(int k=0;k<K;k++){
    acc = fmaf(AT[k*64+b], wp[(long)k*N], acc);
  }
  out[b*N+n] = acc;
}

// ---------------- MFMA GRU step ----------------
// 8 blocks x 4 waves; wave owns 16 h-dims, computes all 6 gate GEMMs (3 gates x {ctx,h}).
// A (ctx,h) staged in 64KB LDS (two K-phases of 256), XOR-swizzled. B from packed Wp.
__global__ __launch_bounds__(256) void k_gru_mfma(
  const unsigned short* __restrict__ ctxprev, const unsigned short* __restrict__ hprevbf,
  const float* __restrict__ hrow_in, float* __restrict__ hrow_out,
  const unsigned short* __restrict__ Wp, const float* __restrict__ gi_emb,
  const float* __restrict__ b_hh, unsigned short* __restrict__ h0bf_all, int t)
{
  __shared__ __align__(16) unsigned short Ash[2*64*256];   // 64KB
  int blk = blockIdx.x;
  int tid = threadIdx.x;
  int w = tid>>6, lane = tid&63;
  int lr = lane&15, lg = lane>>4;
  int swz = (lr&7)<<4;

  f4 acc[6][4];
  #pragma unroll
  for(int u=0;u<6;u++)
    #pragma unroll
    for(int mi=0;mi<4;mi++) acc[u][mi]=(f4)0.f;

  int rgbase = blk*24 + w*6;

  for(int kp=0; kp<2; kp++){
    // stage A: ctx (op0) and h (op1), K-slice [kp*256, kp*256+256)
    for(int c = tid; c < 4096; c += 256){
      int op = c>>11; int row = (c>>5)&63; int kc = c&31;
      const unsigned short* src = (op ? hprevbf : ctxprev) + row*512 + kp*256 + kc*8;
      uint4 v = *(const uint4*)src;
      int dst = op*32768 + row*512 + ((kc*16) ^ ((row&7)<<4));
      *(uint4*)((char*)Ash + dst) = v;
    }
    __syncthreads();
    #pragma unroll 2
    for(int ktl=0; ktl<256; ktl+=32){
      s8v av[2][4];
      #pragma unroll
      for(int op=0;op<2;op++)
        #pragma unroll
        for(int mi=0;mi<4;mi++)
          av[op][mi] = *(const s8v*)((const char*)Ash + op*32768 + (mi*16+lr)*512 + ((ktl*2 + lg*16) ^ swz));
      int ki = kp*8 + (ktl>>5);
      s8v bv[6];
      #pragma unroll
      for(int u=0;u<6;u++)
        bv[u] = *(const s8v*)(Wp + (long)(rgbase+u)*8192 + ki*512 + lane*8);
      #pragma unroll
      for(int u=0;u<6;u++)
        #pragma unroll
        for(int mi=0;mi<4;mi++)
          acc[u][mi] = __builtin_amdgcn_mfma_f32_16x16x32_bf16(av[u&1][mi], bv[u], acc[u][mi], 0,0,0);
    }
    __syncthreads();
  }

  // finish: gates + h update, all in-lane
  int d = blk*64 + w*16 + lr;
  float bhr = b_hh[d], bhz = b_hh[512+d], bhn = b_hh[1024+d];
  #pragma unroll
  for(int mi=0;mi<4;mi++){
    #pragma unroll
    for(int r=0;r<4;r++){
      int b = mi*16 + lg*4 + r;
      const float* ge = gi_emb + (long)(t*64+b)*1536;
      float rr = sigmoidf_(ge[d]      + bhr + acc[0][mi][r] + acc[1][mi][r]);
      float zz = sigmoidf_(ge[512+d]  + bhz + acc[2][mi][r] + acc[3][mi][r]);
      float nn = tanhf_(  ge[1024+d]        + acc[4][mi][r] + rr*(acc[5][mi][r] + bhn));
      float hp = hrow_in[b*512 + d];
      float hv = (1.f-zz)*nn + zz*hp;
      hrow_out[b*512+d] = hv;
      h0bf_all[(long)(t*64+b)*512 + d] = f2bf(hv);
    }
  }
}

// ---------------- MFMA q-GEMM: q[64][512] = h_bf @ Wq_h^T + q_g ----------------
__global__ __launch_bounds__(256) void k_q(
  const unsigned short* __restrict__ hbf, const unsigned short* __restrict__ WqTp,
  const float* __restrict__ q_g, float* __restrict__ qbuf)
{
  int blk = blockIdx.x;
  int tid = threadIdx.x;
  int w = tid>>6, lane = tid&63;
  int lr = lane&15, lg = lane>>4;
  int rg = blk*4 + w;
  f4 acc[4];
  #pragma unroll
  for(int mi=0;mi<4;mi++) acc[mi]=(f4)0.f;
  #pragma unroll 4
  for(int kt=0; kt<512; kt+=32){
    s8v bv = *(const s8v*)(WqTp + (long)rg*8192 + (kt>>5)*512 + lane*8);
    #pragma unroll
    for(int mi=0;mi<4;mi++){
      s8v av = *(const s8v*)(hbf + (mi*16+lr)*512 + kt + lg*8);
      acc[mi] = __builtin_amdgcn_mfma_f32_16x16x32_bf16(av, bv, acc[mi], 0,0,0);
    }
  }
  int n = blk*64 + w*16 + lr;
  #pragma unroll
  for(int mi=0;mi<4;mi++)
    #pragma unroll
    for(int r=0;r<4;r++){
      int m = mi*16 + lg*4 + r;
      qbuf[m*512 + n] = acc[mi][r] + q_g[m*512 + n];
    }
}

// ---------------- attention energy ----------------
__global__ __launch_bounds__(256) void k_energy(
  const unsigned short* __restrict__ pre, const float* __restrict__ q,
  const float* __restrict__ cov, const float* __restrict__ Wv, const float* __restrict__ Wcov,
  const float* __restrict__ pad, float* __restrict__ energy)
{
  int sc = blockIdx.x; int b = blockIdx.y;
  int tid=threadIdx.x; int wid=tid>>6; int lane=tid&63;
  float qv[8], wvv[8], wcv[8];
  #pragma unroll
  for(int kk=0;kk<4;kk++){
    int a0 = kk*128 + lane*2;
    qv[kk*2]=q[b*512+a0]; qv[kk*2+1]=q[b*512+a0+1];
    wvv[kk*2]=Wv[a0]; wvv[kk*2+1]=Wv[a0+1];
    wcv[kk*2]=Wcov[a0]; wcv[kk*2+1]=Wcov[a0+1];
  }
  for(int si=wid; si<50; si+=4){
    int s = sc*50+si;
    float cv = cov[b*400+s];
    const unsigned short* rp = pre + ((long)(b*400+s)<<9);
    float part = 0.f;
    #pragma unroll
    for(int kk=0;kk<4;kk++){
      unsigned u = *(const unsigned*)(rp + kk*128 + lane*2);
      float lo = bf2f((unsigned short)(u&0xffffu));
      float hi = bf2f((unsigned short)(u>>16));
      part += wvv[kk*2]  *tanhf_(lo + qv[kk*2]   + cv*wcv[kk*2]);
      part += wvv[kk*2+1]*tanhf_(hi + qv[kk*2+1] + cv*wcv[kk*2+1]);
    }
    #pragma unroll
    for(int off=32; off; off>>=1) part += __shfl_xor(part, off, 64);
    if(lane==0){
      energy[b*400+s] = (pad[b*400+s] > 0.5f) ? -1e18f : part;
    }
  }
}

// ---------------- softmax + coverage + weighted context ----------------
__global__ __launch_bounds__(256) void k_context(
  const float* __restrict__ energy, float* __restrict__ cov,
  const unsigned short* __restrict__ ctxbf,
  unsigned short* __restrict__ ctx_all, float* __restrict__ outp, int t)
{
  __shared__ float red[256];
  __shared__ float attn_sh[400];
  __shared__ float pb[4][256];
  int ec = blockIdx.x; int b = blockIdx.y; int tid=threadIdx.x;
  float v1 = energy[b*400+tid];
  bool has2 = tid<144;
  float v2 = has2 ? energy[b*400+256+tid] : -INFINITY;
  red[tid] = fmaxf(v1,v2); __syncthreads();
  for(int o=128;o;o>>=1){ if(tid<o) red[tid]=fmaxf(red[tid],red[tid+o]); __syncthreads(); }
  float mx = red[0]; __syncthreads();
  float p1 = __expf(v1-mx); float p2 = has2? __expf(v2-mx) : 0.f;
  red[tid] = p1+p2; __syncthreads();
  for(int o=128;o;o>>=1){ if(tid<o) red[tid]+=red[tid+o]; __syncthreads(); }
  float inv = 1.f/red[0]; __syncthreads();
  float a1 = p1*inv; float a2 = p2*inv;
  attn_sh[tid] = a1; if(has2) attn_sh[256+tid] = a2;
  if(ec==0){
    float* gat = outp + O_GATTN + (long)t*25600 + b*400;
    gat[tid] = a1;
    float c1 = cov[b*400+tid];
    float cl = fminf(a1,c1);
    cov[b*400+tid] = c1+a1;
    if(has2){
      gat[256+tid]=a2;
      float c2 = cov[b*400+256+tid];
      cl += fminf(a2,c2);
      cov[b*400+256+tid] = c2+a2;
    }
    red[tid]=cl; __syncthreads();
    for(int o=128;o;o>>=1){ if(tid<o) red[tid]+=red[tid+o]; __syncthreads(); }
    if(tid==0) outp[O_COVL + t*64 + b] = red[0];
  }
  __syncthreads();
  // phase B: cur_ctx over e-slice [ec*128, ec*128+128)
  int ep = tid&63; int sp = tid>>6;
  int e = ec*128 + ep*2;
  float acc0=0.f, acc1=0.f;
  for(int s=sp; s<400; s+=4){
    float av = attn_sh[s];
    unsigned u = *(const unsigned*)(ctxbf + ((long)(b*400+s)<<9) + e);
    acc0 = fmaf(av, bf2f((unsigned short)(u&0xffffu)), acc0);
    acc1 = fmaf(av, bf2f((unsigned short)(u>>16)), acc1);
  }
  pb[sp][ep*2]=acc0; pb[sp][ep*2+1]=acc1; __syncthreads();
  if(tid<128){
    int c = tid; int eg = ec*128 + c;
    float sum = pb[0][c]+pb[1][c]+pb[2][c]+pb[3][c];
    ctx_all[((long)(t*64+b)<<9)+eg] = f2bf(sum);
    if(t==T_STEPS-1) outp[O_CTXF + b*512 + eg] = sum;
  }
}

// ---------------- post-pass ----------------
__global__ __launch_bounds__(256) void k_pgen(
  const unsigned short* __restrict__ embU, const unsigned short* __restrict__ h0bf,
  const unsigned short* __restrict__ ctxA, const float* __restrict__ Wpg,
  const float* __restrict__ bpg, float* __restrict__ outp)
{
  int wid = threadIdx.x>>6, lane=threadIdx.x&63;
  int m = blockIdx.x*4 + wid;
  float acc=0.f;
  #pragma unroll
  for(int i=0;i<8;i++){
    int k = i*64+lane;
    acc = fmaf(bf2f(ctxA[(long)m*512+k]), Wpg[k], acc);
    acc = fmaf(bf2f(h0bf[(long)m*512+k]), Wpg[512+k], acc);
    acc = fmaf(bf2f(embU[(long)m*512+k]), Wpg[1024+k], acc);
  }
  #pragma unroll
  for(int off=32; off; off>>=1) acc += __shfl_xor(acc, off, 64);
  if(lane==0) outp[O_PG + m] = sigmoidf_(acc + bpg[0]);
}

__global__ void k_maxout(const float* __restrict__ RO, const float* __restrict__ ro_g,
                         float* __restrict__ outp){
  int o = blockIdx.x*256+threadIdx.x; if(o>=819200) return;
  int h = o & 255; int m = o>>8; int b = m & 63;
  float v0 = RO[(long)m*512 + 2*h]   + ro_g[b*512 + 2*h];
  float v1 = RO[(long)m*512 + 2*h+1] + ro_g[b*512 + 2*h+1];
  outp[O_GOUT + o] = fmaxf(v0,v1);
}

__global__ void k_final(const float* __restrict__ hrowF, const float* __restrict__ cov,
                        float* __restrict__ outp){
  int o = blockIdx.x*256+threadIdx.x;
  if(o < 32768){ outp[O_HID + o] = hrowF[o]; }
  else if(o < 58368){ int p=o-32768; outp[O_ATTN_LAST+p] = outp[O_GATTN + 49*25600 + p]; }
  else if(o < 83968){ int p=o-58368; outp[O_COVF+p] = cov[p]; }
}

extern "C" void kernel_launch(void* const* d_in, const int* in_sizes, int n_in,
                              void* d_out, int out_size, void* d_ws, size_t ws_size,
                              hipStream_t stream)
{
  (void)in_sizes; (void)n_in; (void)out_size; (void)ws_size;
  const int*   y       = (const int*)d_in[0];
  const float* hidden  = (const float*)d_in[1];
  const float* context = (const float*)d_in[2];
  const float* padm    = (const float*)d_in[3];
  const float* init_att= (const float*)d_in[4];
  const float* coverage= (const float*)d_in[5];
  const float* gctx    = (const float*)d_in[6];
  const float* embW    = (const float*)d_in[7];
  const float* W_ih    = (const float*)d_in[8];
  const float* W_hh    = (const float*)d_in[9];
  const float* b_ih    = (const float*)d_in[10];
  const float* b_hh    = (const float*)d_in[11];
  const float* W_pre   = (const float*)d_in[12];
  const float* b_pre   = (const float*)d_in[13];
  const float* W_q     = (const float*)d_in[14];
  const float* W_v     = (const float*)d_in[15];
  const float* W_cov   = (const float*)d_in[16];
  const float* W_pg    = (const float*)d_in[17];
  const float* b_pg    = (const float*)d_in[18];
  const float* W_ro    = (const float*)d_in[19];
  const float* b_ro    = (const float*)d_in[20];
  float* out = (float*)d_out;

  char* wsb = (char*)d_ws;
  size_t off = 0;
  auto alloc = [&](size_t bytes)->char*{ char* p = wsb+off; off += (bytes+255)&~255UL; return p; };
  unsigned short* pre    = (unsigned short*)alloc(25600UL*512*2);
  unsigned short* ctxbf  = (unsigned short*)alloc(13107200UL*2);
  unsigned short* embU   = (unsigned short*)alloc(3200UL*512*2);
  unsigned short* wihbf  = (unsigned short*)alloc(1536UL*512*2);
  unsigned short* wpreT  = (unsigned short*)alloc(512UL*512*2);
  unsigned short* wroT   = (unsigned short*)alloc(512UL*2048*2);
  unsigned short* Wgru   = (unsigned short*)alloc(192UL*8192*2);   // 3MB packed GRU weights
  unsigned short* WqTp   = (unsigned short*)alloc(32UL*8192*2);    // 0.5MB packed W_q(h)
  float* gi_emb = (float*)alloc(3200UL*1536*4);
  float* RO     = (float*)alloc(3200UL*512*4);
  float* q_g    = (float*)alloc(64UL*512*4);
  float* ro_g   = (float*)alloc(64UL*512*4);
  float* hrow0  = (float*)alloc(64UL*512*4);
  float* hrow1  = (float*)alloc(64UL*512*4);
  float* gctxT  = (float*)alloc(512UL*64*4);
  unsigned short* h0bf = (unsigned short*)alloc(3200UL*512*2);
  unsigned short* h0bf_init = (unsigned short*)alloc(64UL*512*2);
  unsigned short* ctx0bf    = (unsigned short*)alloc(64UL*512*2);
  unsigned short* ctxA = (unsigned short*)alloc(3200UL*512*2);
  float* qbuf   = (float*)alloc(64UL*512*4);
  float* energy = (float*)alloc(64UL*400*4);
  float* cov    = (float*)alloc(64UL*400*4);

  // converts + init
  conv_ctx <<<dim3(51200),dim3(256),0,stream>>>(context, ctxbf);
  conv_emb <<<dim3(6400), dim3(256),0,stream>>>(y, embW, embU);
  conv_wihd<<<dim3(3072), dim3(256),0,stream>>>(W_ih, wihbf);
  conv_preT<<<dim3(1024), dim3(256),0,stream>>>(W_pre, wpreT);
  conv_roT <<<dim3(4096), dim3(256),0,stream>>>(W_ro, wroT);
  conv_wgru<<<dim3(6144), dim3(256),0,stream>>>(W_ih, W_hh, Wgru);
  conv_wq  <<<dim3(1024), dim3(256),0,stream>>>(W_q, WqTp);
  k_init   <<<dim3(485),  dim3(256),0,stream>>>(hidden, init_att, gctx, coverage,
                                                hrow0, h0bf_init, ctx0bf, gctxT, cov);

  // precompute GEMMs
  mfma_gemm<1,0><<<dim3(200,4),dim3(256),0,stream>>>(ctxbf,512, wpreT,512,0,  pre,   512, b_pre, 512);
  mfma_gemm<0,0><<<dim3(25,12),dim3(256),0,stream>>>(embU, 512, wihbf,512,0,  gi_emb,1536,b_ih, 512);
  mfma_gemm<0,0><<<dim3(25,4), dim3(256),0,stream>>>(embU, 512, wroT,2048,0,  RO,    512, b_ro, 512);
  small_gemm_kn<<<dim3(128),dim3(256),0,stream>>>(gctxT, W_q, 512, 512, nullptr, q_g, 512);
  small_gemm_kn<<<dim3(128),dim3(256),0,stream>>>(gctxT, W_ro,1536, 512, nullptr, ro_g, 512);

  // scan
  for(int t=0; t<T_STEPS; t++){
    float* hin  = (t&1) ? hrow1 : hrow0;
    float* hout = (t&1) ? hrow0 : hrow1;
    const unsigned short* ctxprev = (t==0) ? ctx0bf : (ctxA + (long)(t-1)*32768);
    const unsigned short* hprevbf = (t==0) ? h0bf_init : (h0bf + (long)(t-1)*32768);
    k_gru_mfma<<<dim3(8),dim3(256),0,stream>>>(ctxprev, hprevbf, hin, hout,
                                               Wgru, gi_emb, b_hh, h0bf, t);
    k_q<<<dim3(8),dim3(256),0,stream>>>(h0bf + (long)t*32768, WqTp, q_g, qbuf);
    k_energy<<<dim3(8,64),dim3(256),0,stream>>>(pre, qbuf, cov, W_v, W_cov, padm, energy);
    k_context<<<dim3(4,64),dim3(256),0,stream>>>(energy, cov, ctxbf, ctxA, out, t);
  }

  // post-pass
  mfma_gemm<0,1><<<dim3(25,4),dim3(256),0,stream>>>(h0bf,512, wroT,2048,512,  RO,512, nullptr, 512);
  mfma_gemm<0,1><<<dim3(25,4),dim3(256),0,stream>>>(ctxA,512, wroT,2048,1024, RO,512, nullptr, 512);
  k_pgen  <<<dim3(800), dim3(256),0,stream>>>(embU, h0bf, ctxA, W_pg, b_pg, out);
  k_maxout<<<dim3(3200),dim3(256),0,stream>>>(RO, ro_g, out);
  k_final <<<dim3(328), dim3(256),0,stream>>>(hrow0, cov, out);
}